// Round 14
// baseline (363.363 us; speedup 1.0000x reference)
//
#include <hip/hip_runtime.h>

#define NND 50000
#define NED 800000
#define NF  128
#define NH  64
#define BN_EPS 1e-5
#define NCOPY 8    // stats slot-copies (f32)
#define SCB  256   // scan chunk
#define NSB  ((NND + SCB - 1) / SCB)   // 196 scan blocks
#define XNODES (NND / 8)               // 6250 nodes per XCD slice
#define FCH  196                       // edge chunks (1024 int4 each) per XCD pass
#define NT   782                       // transform/mlp tiles
#define PGRID (FCH * 8)                // 1568 edge-partition blocks
#define NE4  (NED / 4)                 // 200000 int4 edge quads

// ---- workspace byte offsets (16B aligned) ----
#define WS_HB     0                          // bf16[NND*64]  (h, gather source)   6,400,000 B
#define WS_AGG    6400000                    // bf16[NND*64]  (agg, MLP input)     6,400,000 B
#define WS_STATS  12800000                   // float[4][NCOPY*128] = 16 KB (4 stages, memset each call)
#define WS_DEG    (WS_STATS + 4*NCOPY*128*4) // int[NND]  (memset'd with stats)
#define WS_OFFS   (WS_DEG + NND*4)           // int[NND+4]
#define WS_CUR    (WS_OFFS + (NND+4)*4)      // int[NND]
#define WS_PARTS  (WS_CUR + NND*4)           // int[256]
#define WS_ESRC   (WS_PARTS + 256*4)         // int[NED]

// ---- bf16 helpers (storage-only; all math in f32) ----
__device__ __forceinline__ unsigned bfrn(float x) {          // f32 -> bf16 (RTN-even)
    unsigned u = __float_as_uint(x);
    return (u + 0x7fffu + ((u >> 16) & 1u)) >> 16;
}
__device__ __forceinline__ unsigned pk(float lo, float hi) { // 2x f32 -> packed bf16x2
    return bfrn(lo) | (bfrn(hi) << 16);
}
__device__ __forceinline__ float ulo(unsigned u) { return __uint_as_float(u << 16); }
__device__ __forceinline__ float uhi(unsigned u) { return __uint_as_float(u & 0xffff0000u); }
__device__ __forceinline__ void upadd(unsigned u, float& lo, float& hi) {
    lo += ulo(u); hi += uhi(u);
}
// weighted accumulate (w=0 masks clamped-duplicate gathers)
__device__ __forceinline__ void upaddw(unsigned u, float w, float& lo, float& hi) {
    lo = fmaf(w, ulo(u), lo); hi = fmaf(w, uhi(u), hi);
}

// derive BN scale/shift for column c from f32 slot-copy stats
__device__ __forceinline__ void bn_derive(const float* __restrict__ st, int c,
                                          const float* __restrict__ g,
                                          const float* __restrict__ b,
                                          float& sc, float& sh) {
    float sum = 0.f, ssq = 0.f;
#pragma unroll
    for (int cp = 0; cp < NCOPY; ++cp) {
        sum += st[cp * 128 + c];
        ssq += st[cp * 128 + 64 + c];
    }
    double mu  = (double)sum / (double)NND;
    double var = (double)ssq / (double)NND - mu * mu;
    if (var < 0.0) var = 0.0;
    double rs = 1.0 / sqrt(var + BN_EPS);
    double scd = (double)g[c] * rs;
    sc = (float)scd;
    sh = (float)((double)b[c] - mu * scd);
}

// ---------------- FUSED: transform (blocks [0,NT)) || degree count (blocks [NT,NT+PGRID)) ----
__global__ __launch_bounds__(256) void k_dtf(const int* __restrict__ dst,
                                             int* __restrict__ deg,
                                             const float* __restrict__ x,
                                             const float* __restrict__ Wt,
                                             const float* __restrict__ bt,
                                             unsigned* __restrict__ hB,
                                             float* __restrict__ stats) {
    __shared__ __align__(16) unsigned Wlu[NF * NH / 2]; // 16 KB, bf16-packed
    __shared__ __align__(16) float sT[64 * 68];         // 17.4 KB
    int tid = threadIdx.x;

    if (blockIdx.x >= NT) {
        // ---- degree-count body: batch all 4 stream loads up-front (ILP) ----
        int dbid = blockIdx.x - NT;
        int xcd = dbid & 7;
        int chunk = dbid >> 3;
        int lo = xcd * XNODES;
        const int4* d4 = (const int4*)dst;
        int4 d[4];
#pragma unroll
        for (int r = 0; r < 4; ++r) {
            int i = chunk * 1024 + r * 256 + tid;
            int ii = i < NE4 ? i : NE4 - 1;
            d[r] = d4[ii];
            if (i >= NE4) d[r] = make_int4(-1, -1, -1, -1);
        }
#pragma unroll
        for (int r = 0; r < 4; ++r) {
            if ((unsigned)(d[r].x - lo) < XNODES) atomicAdd(&deg[d[r].x], 1);
            if ((unsigned)(d[r].y - lo) < XNODES) atomicAdd(&deg[d[r].y], 1);
            if ((unsigned)(d[r].z - lo) < XNODES) atomicAdd(&deg[d[r].z], 1);
            if ((unsigned)(d[r].w - lo) < XNODES) atomicAdd(&deg[d[r].w], 1);
        }
        return;
    }

    // ---- transform body: one 64-node tile; all 256 threads stage, waves 0-1 compute ----
    int tile = blockIdx.x;
    int base = tile * 64;
    const float4* x4 = (const float4*)x;

#pragma unroll
    for (int r = 0; r < 8; ++r) {
        int i4 = r * 256 + tid;
        float4 w = ((const float4*)Wt)[i4];
        uint2 wp; wp.x = pk(w.x, w.y); wp.y = pk(w.z, w.w);
        ((uint2*)Wlu)[i4] = wp;
    }

    int wave = tid >> 6, lane = tid & 63;
    int ti = lane & 7, tj = lane >> 3;
    int cw = wave * 32 + tj * 4;          // compute waves 0-1: output cols

    float acc[8][4];
#pragma unroll
    for (int i = 0; i < 8; ++i)
#pragma unroll
        for (int j = 0; j < 4; ++j) acc[i][j] = 0.f;

    for (int ch = 0; ch < 2; ++ch) {
        __syncthreads();
        float4 pf[4];
#pragma unroll
        for (int s = 0; s < 4; ++s) {
            int flat = s * 256 + tid;
            int nl = flat >> 4, q = flat & 15;
            pf[s] = make_float4(0.f, 0.f, 0.f, 0.f);
            if (base + nl < NND) pf[s] = x4[(size_t)(base + nl) * 32 + ch * 16 + q];
        }
#pragma unroll
        for (int s = 0; s < 4; ++s) {
            int flat = s * 256 + tid;
            int nl = flat >> 4, q = flat & 15;
            sT[(q * 4 + 0) * 68 + nl] = pf[s].x;
            sT[(q * 4 + 1) * 68 + nl] = pf[s].y;
            sT[(q * 4 + 2) * 68 + nl] = pf[s].z;
            sT[(q * 4 + 3) * 68 + nl] = pf[s].w;
        }
        __syncthreads();
        if (tid < 128) {
#pragma unroll 4
            for (int k = 0; k < 64; ++k) {
                const float* ap = &sT[k * 68 + ti * 8];
                float4 alo = *(const float4*)ap;
                float4 ahi = *(const float4*)(ap + 4);
                uint2 wu = *(const uint2*)&Wlu[(ch * 64 + k) * 32 + (cw >> 1)];
                float a8[8] = {alo.x, alo.y, alo.z, alo.w, ahi.x, ahi.y, ahi.z, ahi.w};
                float w4[4] = {ulo(wu.x), uhi(wu.x), ulo(wu.y), uhi(wu.y)};
#pragma unroll
                for (int i = 0; i < 8; ++i)
#pragma unroll
                    for (int j = 0; j < 4; ++j) acc[i][j] += a8[i] * w4[j];
            }
        }
    }
    if (tid >= 128) return;

    float4 bv = *(const float4*)&bt[cw];
    float bj[4] = {bv.x, bv.y, bv.z, bv.w};

    float s4[4] = {0.f, 0.f, 0.f, 0.f}, q4[4] = {0.f, 0.f, 0.f, 0.f};
    uint2* hB2 = (uint2*)hB;
#pragma unroll
    for (int i = 0; i < 8; ++i) {
        int n = base + ti * 8 + i;
        if (n < NND) {
            float o[4];
#pragma unroll
            for (int j = 0; j < 4; ++j) {
                o[j] = acc[i][j] + bj[j];
                s4[j] += o[j];
                q4[j] += o[j] * o[j];
            }
            uint2 ov; ov.x = pk(o[0], o[1]); ov.y = pk(o[2], o[3]);
            hB2[(size_t)n * 16 + wave * 8 + tj] = ov;
        }
    }
#pragma unroll
    for (int m = 1; m < 8; m <<= 1) {
#pragma unroll
        for (int j = 0; j < 4; ++j) {
            s4[j] += __shfl_xor(s4[j], m);
            q4[j] += __shfl_xor(q4[j], m);
        }
    }
    if (ti == 0) {
        int slot = (tile & (NCOPY - 1)) * 128;
#pragma unroll
        for (int j = 0; j < 4; ++j) {
            atomicAdd(&stats[slot + cw + j], s4[j]);
            atomicAdd(&stats[slot + 64 + cw + j], q4[j]);
        }
    }
}

// ---------------- CSR fill: batch all 8 stream loads up-front (ILP) ----------------
__global__ __launch_bounds__(256) void k_fill(const int* __restrict__ src,
                                              const int* __restrict__ dst,
                                              int* __restrict__ cur,
                                              int* __restrict__ esrc) {
    int xcd = blockIdx.x & 7;
    int chunk = blockIdx.x >> 3;
    int lo = xcd * XNODES;
    const int4* d4 = (const int4*)dst;
    const int4* s4 = (const int4*)src;
    int4 d[4], s[4];
#pragma unroll
    for (int r = 0; r < 4; ++r) {
        int i = chunk * 1024 + r * 256 + threadIdx.x;
        int ii = i < NE4 ? i : NE4 - 1;
        d[r] = d4[ii];
        s[r] = s4[ii];
        if (i >= NE4) d[r] = make_int4(-1, -1, -1, -1);
    }
#pragma unroll
    for (int r = 0; r < 4; ++r) {
        if ((unsigned)(d[r].x - lo) < XNODES) esrc[atomicAdd(&cur[d[r].x], 1)] = s[r].x;
        if ((unsigned)(d[r].y - lo) < XNODES) esrc[atomicAdd(&cur[d[r].y], 1)] = s[r].y;
        if ((unsigned)(d[r].z - lo) < XNODES) esrc[atomicAdd(&cur[d[r].z], 1)] = s[r].z;
        if ((unsigned)(d[r].w - lo) < XNODES) esrc[atomicAdd(&cur[d[r].w], 1)] = s[r].w;
    }
}

__global__ __launch_bounds__(SCB) void k_part(const int* __restrict__ deg,
                                              int* __restrict__ offs,
                                              int* __restrict__ parts) {
    __shared__ int sd[SCB];
    int t = threadIdx.x;
    int i = blockIdx.x * SCB + t;
    int v = (i < NND) ? deg[i] : 0;
    sd[t] = v;
    __syncthreads();
#pragma unroll
    for (int off = 1; off < SCB; off <<= 1) {
        int u = (t >= off) ? sd[t - off] : 0;
        __syncthreads();
        sd[t] += u;
        __syncthreads();
    }
    if (i < NND) offs[i] = sd[t] - v;
    if (t == SCB - 1) parts[blockIdx.x] = sd[t];
}

__global__ __launch_bounds__(256) void k_scan2(int* __restrict__ parts) {
    __shared__ int sd[256];
    int t = threadIdx.x;
    int v = (t < NSB) ? parts[t] : 0;
    sd[t] = v;
    __syncthreads();
#pragma unroll
    for (int off = 1; off < 256; off <<= 1) {
        int u = (t >= off) ? sd[t - off] : 0;
        __syncthreads();
        sd[t] += u;
        __syncthreads();
    }
    if (t < NSB) parts[t] = sd[t] - v;
}

__global__ __launch_bounds__(256) void k_apply(int* __restrict__ offs,
                                               const int* __restrict__ parts,
                                               int* __restrict__ cur) {
    int i = blockIdx.x * 256 + threadIdx.x;
    if (i < NND) {
        int o = offs[i] + parts[i >> 8];
        offs[i] = o;
        cur[i] = o;
    }
    if (i == NND) offs[NND] = NED;
}

// ---------------- aggregation v2: wave-per-node, 16 edge slots x 4 lanes x 32B ----------------
// All <=64 edges of a node issue in ONE load round (2 uint4/lane/group, groups
// skipped by wave-uniform branch, partial groups masked by per-lane weight on a
// clamped-duplicate index). 2x the in-flight loads of the 8-slot version.
__global__ __launch_bounds__(256) void k_agg(const uint4* __restrict__ hB4,
                                             uint4* __restrict__ aggB4,
                                             const float* __restrict__ stats,
                                             const float* __restrict__ g,
                                             const float* __restrict__ b,
                                             const int* __restrict__ offs,
                                             const int* __restrict__ esrc) {
    int tid  = threadIdx.x;
    int lane = tid & 63;
    int wv   = tid >> 6;
    int n = blockIdx.x * 4 + wv;
    int q2 = lane & 3;       // 32B chunk: uint4 pair q2*2, q2*2+1 (cols q2*16..+15)
    int r  = lane >> 2;      // edge slot 0..15

    // per-lane BN derive for column `lane` (L2-hot 4KB)
    float scl, shl;
    bn_derive(stats, lane, g, b, scl, shl);

    int e0 = offs[n], e1 = offs[n + 1];
    int deg = e1 - e0;

    float a[16];
#pragma unroll
    for (int i = 0; i < 16; ++i) a[i] = 0.f;

    if (r == 0) {            // self row: 4 lanes x 32B
        uint4 ua = hB4[(size_t)n * 8 + q2 * 2];
        uint4 ub = hB4[(size_t)n * 8 + q2 * 2 + 1];
        upadd(ua.x, a[0], a[1]);  upadd(ua.y, a[2], a[3]);
        upadd(ua.z, a[4], a[5]);  upadd(ua.w, a[6], a[7]);
        upadd(ub.x, a[8], a[9]);  upadd(ub.y, a[10], a[11]);
        upadd(ub.z, a[12], a[13]); upadd(ub.w, a[14], a[15]);
    }

    for (int bb = e0; bb < e1; bb += 64) {
        int m = e1 - bb; if (m > 64) m = 64;
        int idx = (lane < m) ? esrc[bb + lane] : 0;
        int jj[4]; float w[4];
        uint4 ua[4], ub[4];
        // issue phase: all groups' loads back-to-back (wave-uniform skip per group)
#pragma unroll
        for (int gi = 0; gi < 4; ++gi) {
            if (gi * 16 < m) {
                int e = gi * 16 + r;
                int ec = e < m ? e : m - 1;
                jj[gi] = __shfl(idx, ec);
                w[gi]  = e < m ? 1.f : 0.f;
                ua[gi] = hB4[(size_t)jj[gi] * 8 + q2 * 2];
                ub[gi] = hB4[(size_t)jj[gi] * 8 + q2 * 2 + 1];
            }
        }
        // accumulate phase
#pragma unroll
        for (int gi = 0; gi < 4; ++gi) {
            if (gi * 16 < m) {
                float wg = w[gi];
                upaddw(ua[gi].x, wg, a[0], a[1]);   upaddw(ua[gi].y, wg, a[2], a[3]);
                upaddw(ua[gi].z, wg, a[4], a[5]);   upaddw(ua[gi].w, wg, a[6], a[7]);
                upaddw(ub[gi].x, wg, a[8], a[9]);   upaddw(ub[gi].y, wg, a[10], a[11]);
                upaddw(ub[gi].z, wg, a[12], a[13]); upaddw(ub[gi].w, wg, a[14], a[15]);
            }
        }
    }

    // reduce across the 16 edge slots (lane bits 2..5); q2 preserved
#pragma unroll
    for (int msk = 4; msk <= 32; msk <<= 1)
#pragma unroll
        for (int i = 0; i < 16; ++i) a[i] += __shfl_xor(a[i], msk);

    // gather the 16 (sc,sh) pairs for this lane's columns q2*16..q2*16+15
    float sc16[16], sh16[16];
#pragma unroll
    for (int j = 0; j < 16; ++j) {
        sc16[j] = __shfl(scl, q2 * 16 + j);
        sh16[j] = __shfl(shl, q2 * 16 + j);
    }

    if (r == 0) {
        float dn = (float)(deg + 1);
        float o[16];
#pragma unroll
        for (int j = 0; j < 16; ++j) o[j] = sc16[j] * a[j] + dn * sh16[j];
        uint4 ova, ovb;
        ova.x = pk(o[0], o[1]);   ova.y = pk(o[2], o[3]);
        ova.z = pk(o[4], o[5]);   ova.w = pk(o[6], o[7]);
        ovb.x = pk(o[8], o[9]);   ovb.y = pk(o[10], o[11]);
        ovb.z = pk(o[12], o[13]); ovb.w = pk(o[14], o[15]);
        aggB4[(size_t)n * 8 + q2 * 2]     = ova;
        aggB4[(size_t)n * 8 + q2 * 2 + 1] = ovb;
    }
}

// ---------------- MLP: col-split 1-tile blocks (2 waves, acc 8x4), 2 GEMMs ----------------
__global__ __launch_bounds__(128) void k_mlp(const uint4* __restrict__ aggB4,
                                             float* __restrict__ outF,    // f32 out (last layer) or null
                                             unsigned* __restrict__ hBo,  // bf16 out or null
                                             float* __restrict__ stats,
                                             const float* __restrict__ W1,
                                             const float* __restrict__ W2) {
    __shared__ __align__(16) float W1l[NH * NH];  // 16 KB
    __shared__ __align__(16) float W2l[NH * NH];  // 16 KB
    __shared__ __align__(16) float sT[64 * 68];   // 17.4 KB (agg, then t1)
    int tid  = threadIdx.x;
    int wave = tid >> 6, lane = tid & 63;
    int ti = lane & 7, tj = lane >> 3;
    int tile = blockIdx.x;
    int base = tile * 64;
    int cw = wave * 32 + tj * 4;

#pragma unroll
    for (int r = 0; r < 8; ++r) {
        int i4 = r * 128 + tid;
        ((float4*)W1l)[i4] = ((const float4*)W1)[i4];
        ((float4*)W2l)[i4] = ((const float4*)W2)[i4];
    }
#pragma unroll
    for (int s = 0; s < 4; ++s) {
        int i4 = s * 128 + tid;
        int nl = i4 >> 3, q = i4 & 7;
        uint4 u = make_uint4(0u, 0u, 0u, 0u);
        if (base + nl < NND) u = aggB4[(size_t)(base + nl) * 8 + q];
        sT[(q * 8 + 0) * 68 + nl] = ulo(u.x);
        sT[(q * 8 + 1) * 68 + nl] = uhi(u.x);
        sT[(q * 8 + 2) * 68 + nl] = ulo(u.y);
        sT[(q * 8 + 3) * 68 + nl] = uhi(u.y);
        sT[(q * 8 + 4) * 68 + nl] = ulo(u.z);
        sT[(q * 8 + 5) * 68 + nl] = uhi(u.z);
        sT[(q * 8 + 6) * 68 + nl] = ulo(u.w);
        sT[(q * 8 + 7) * 68 + nl] = uhi(u.w);
    }
    __syncthreads();

    float a1[8][4];
#pragma unroll
    for (int i = 0; i < 8; ++i)
#pragma unroll
        for (int j = 0; j < 4; ++j) a1[i][j] = 0.f;
#pragma unroll 4
    for (int k = 0; k < 64; ++k) {
        const float* ap = &sT[k * 68 + ti * 8];
        float4 alo = *(const float4*)ap;
        float4 ahi = *(const float4*)(ap + 4);
        float4 wv  = *(const float4*)&W1l[k * NH + cw];
        float a8[8] = {alo.x, alo.y, alo.z, alo.w, ahi.x, ahi.y, ahi.z, ahi.w};
        float w4[4] = {wv.x, wv.y, wv.z, wv.w};
#pragma unroll
        for (int i = 0; i < 8; ++i)
#pragma unroll
            for (int j = 0; j < 4; ++j) a1[i][j] += a8[i] * w4[j];
    }
#pragma unroll
    for (int i = 0; i < 8; ++i)
#pragma unroll
        for (int j = 0; j < 4; ++j) a1[i][j] = fmaxf(a1[i][j], 0.f);

    __syncthreads();
#pragma unroll
    for (int j = 0; j < 4; ++j) {
        float* p = &sT[(cw + j) * 68 + ti * 8];
        float4 lo = {a1[0][j], a1[1][j], a1[2][j], a1[3][j]};
        float4 hi = {a1[4][j], a1[5][j], a1[6][j], a1[7][j]};
        *(float4*)p = lo;
        *(float4*)(p + 4) = hi;
    }
    __syncthreads();

    float a2[8][4];
#pragma unroll
    for (int i = 0; i < 8; ++i)
#pragma unroll
        for (int j = 0; j < 4; ++j) a2[i][j] = 0.f;
#pragma unroll 4
    for (int k = 0; k < 64; ++k) {
        const float* ap = &sT[k * 68 + ti * 8];
        float4 alo = *(const float4*)ap;
        float4 ahi = *(const float4*)(ap + 4);
        float4 wv  = *(const float4*)&W2l[k * NH + cw];
        float a8[8] = {alo.x, alo.y, alo.z, alo.w, ahi.x, ahi.y, ahi.z, ahi.w};
        float w4[4] = {wv.x, wv.y, wv.z, wv.w};
#pragma unroll
        for (int i = 0; i < 8; ++i)
#pragma unroll
            for (int j = 0; j < 4; ++j) a2[i][j] += a8[i] * w4[j];
    }

    float s4[4] = {0.f, 0.f, 0.f, 0.f}, q4[4] = {0.f, 0.f, 0.f, 0.f};
    uint2* hBo2 = (uint2*)hBo;
#pragma unroll
    for (int i = 0; i < 8; ++i) {
        int n = base + ti * 8 + i;
        if (n < NND) {
            float o[4];
#pragma unroll
            for (int j = 0; j < 4; ++j) {
                o[j] = fmaxf(a2[i][j], 0.f);
                s4[j] += o[j];
                q4[j] += o[j] * o[j];
            }
            if (outF) *(float4*)&outF[(size_t)n * NH + cw] = *(float4*)&o[0];
            if (hBo) {
                uint2 ov; ov.x = pk(o[0], o[1]); ov.y = pk(o[2], o[3]);
                hBo2[(size_t)n * 16 + wave * 8 + tj] = ov;
            }
        }
    }
#pragma unroll
    for (int m = 1; m < 8; m <<= 1) {
#pragma unroll
        for (int j = 0; j < 4; ++j) {
            s4[j] += __shfl_xor(s4[j], m);
            q4[j] += __shfl_xor(q4[j], m);
        }
    }
    if (ti == 0) {
        int slot = (tile & (NCOPY - 1)) * 128;
#pragma unroll
        for (int j = 0; j < 4; ++j) {
            atomicAdd(&stats[slot + cw + j], s4[j]);
            atomicAdd(&stats[slot + 64 + cw + j], q4[j]);
        }
    }
}

// ---------------- final BN apply, in-place on f32 out; sc/sh derived per block ----------------
__global__ __launch_bounds__(256) void k_bnout(float* __restrict__ h,
                                               const float* __restrict__ stats,
                                               const float* __restrict__ g,
                                               const float* __restrict__ b) {
    __shared__ float sl[128];
    int tid = threadIdx.x;
    if (tid < 64) {
        float sc, sh;
        bn_derive(stats, tid, g, b, sc, sh);
        sl[tid]      = sc;
        sl[64 + tid] = sh;
    }
    __syncthreads();
    int i4 = blockIdx.x * 256 + tid;
    if (i4 < NND * NH / 4) {
        int cg = i4 & 15;
        float4 v   = ((float4*)h)[i4];
        float4 scv = *(float4*)&sl[cg * 4];
        float4 shv = *(float4*)&sl[64 + cg * 4];
        v.x = v.x * scv.x + shv.x;
        v.y = v.y * scv.y + shv.y;
        v.z = v.z * scv.z + shv.z;
        v.w = v.w * scv.w + shv.w;
        ((float4*)h)[i4] = v;
    }
}

extern "C" void kernel_launch(void* const* d_in, const int* in_sizes, int n_in,
                              void* d_out, int out_size, void* d_ws, size_t ws_size,
                              hipStream_t stream) {
    const float* x     = (const float*)d_in[0];
    const int*   ei    = (const int*)d_in[1];
    const float* Wt    = (const float*)d_in[2];
    const float* bt    = (const float*)d_in[3];
    const float* gt    = (const float*)d_in[4];
    const float* bbt   = (const float*)d_in[5];
    const float* W1    = (const float*)d_in[6];
    const float* W2    = (const float*)d_in[7];
    const float* gamma = (const float*)d_in[8];
    const float* beta  = (const float*)d_in[9];
    float* out = (float*)d_out;

    char* ws = (char*)d_ws;
    unsigned* hB    = (unsigned*)(ws + WS_HB);
    unsigned* aggB  = (unsigned*)(ws + WS_AGG);
    float*    stats = (float*)(ws + WS_STATS);   // 4 stage buffers of NCOPY*128
    int*      deg   = (int*)(ws + WS_DEG);
    int*      offs  = (int*)(ws + WS_OFFS);
    int*      cur   = (int*)(ws + WS_CUR);
    int*      parts = (int*)(ws + WS_PARTS);
    int*      esrc  = (int*)(ws + WS_ESRC);

    float* st0 = stats;
    float* st1 = stats + NCOPY * 128;
    float* st2 = stats + 2 * NCOPY * 128;
    float* st3 = stats + 3 * NCOPY * 128;

    const int* srcv = ei;
    const int* dstv = ei + NED;

    // one memset covers all 4 stat buffers + deg (contiguous)
    hipMemsetAsync(stats, 0, 4 * NCOPY * 128 * 4 + NND * 4, stream);

    // fused transform || degree count
    k_dtf<<<NT + PGRID, 256, 0, stream>>>(dstv, deg, x, Wt, bt, hB, st0);
    k_part<<<NSB, SCB, 0, stream>>>(deg, offs, parts);
    k_scan2<<<1, 256, 0, stream>>>(parts);
    k_apply<<<NSB, 256, 0, stream>>>(offs, parts, cur);
    k_fill<<<PGRID, 256, 0, stream>>>(srcv, dstv, cur, esrc);

    const int NB = NND / 4;         // 12500 agg blocks

    // layer 0: BN(st0; g_t) folded into agg
    k_agg<<<NB, 256, 0, stream>>>((const uint4*)hB, (uint4*)aggB, st0, gt, bbt, offs, esrc);
    k_mlp<<<NT, 128, 0, stream>>>((const uint4*)aggB, nullptr, hB, st1, W1, W2);

    // layer 1: BN(st1; gamma[0]) folded into agg
    k_agg<<<NB, 256, 0, stream>>>((const uint4*)hB, (uint4*)aggB, st1, gamma, beta, offs, esrc);
    k_mlp<<<NT, 128, 0, stream>>>((const uint4*)aggB, nullptr, hB, st2, W1 + 4096, W2 + 4096);

    // layer 2: BN(st2; gamma[1]) folded into agg; f32 out for final BN
    k_agg<<<NB, 256, 0, stream>>>((const uint4*)hB, (uint4*)aggB, st2, gamma + 64, beta + 64, offs, esrc);
    k_mlp<<<NT, 128, 0, stream>>>((const uint4*)aggB, out, nullptr, st3, W1 + 8192, W2 + 8192);

    // final BN apply (BN(st3; gamma[2]) derived per block)
    k_bnout<<<(NND * NH / 4 + 255) / 256, 256, 0, stream>>>(out, st3, gamma + 128, beta + 128);
}

// Round 15
// 302.506 us; speedup vs baseline: 1.2012x; 1.2012x over previous
//
#include <hip/hip_runtime.h>

#define NND 50000
#define NED 800000
#define NF  128
#define NH  64
#define BN_EPS 1e-5
#define NCOPY 8    // stats slot-copies (f32)
#define SCB  256   // scan chunk
#define NSB  ((NND + SCB - 1) / SCB)   // 196 scan blocks
#define XNODES (NND / 8)               // 6250 nodes per XCD slice
#define FCH  196                       // edge chunks (1024 int4 each) per XCD pass
#define NT   782                       // transform/mlp tiles
#define PGRID (FCH * 8)                // 1568 edge-partition blocks
#define NE4  (NED / 4)                 // 200000 int4 edge quads

// ---- workspace byte offsets (16B aligned) ----
#define WS_HB     0                          // bf16[NND*64]  (h, gather source)   6,400,000 B
#define WS_AGG    6400000                    // bf16[NND*64]  (agg, MLP input)     6,400,000 B
#define WS_STATS  12800000                   // float[4][NCOPY*128] = 16 KB (4 stages, memset each call)
#define WS_DEG    (WS_STATS + 4*NCOPY*128*4) // int[NND]  (memset'd with stats)
#define WS_OFFS   (WS_DEG + NND*4)           // int[NND+4]
#define WS_CUR    (WS_OFFS + (NND+4)*4)      // int[NND]
#define WS_PARTS  (WS_CUR + NND*4)           // int[256]
#define WS_ESRC   (WS_PARTS + 256*4)         // int[NED]

// ---- bf16 helpers (storage-only; all math in f32) ----
__device__ __forceinline__ unsigned bfrn(float x) {          // f32 -> bf16 (RTN-even)
    unsigned u = __float_as_uint(x);
    return (u + 0x7fffu + ((u >> 16) & 1u)) >> 16;
}
__device__ __forceinline__ unsigned pk(float lo, float hi) { // 2x f32 -> packed bf16x2
    return bfrn(lo) | (bfrn(hi) << 16);
}
__device__ __forceinline__ float ulo(unsigned u) { return __uint_as_float(u << 16); }
__device__ __forceinline__ float uhi(unsigned u) { return __uint_as_float(u & 0xffff0000u); }
__device__ __forceinline__ void upadd(unsigned u, float& lo, float& hi) {
    lo += ulo(u); hi += uhi(u);
}

// derive BN scale/shift for column c from f32 slot-copy stats
__device__ __forceinline__ void bn_derive(const float* __restrict__ st, int c,
                                          const float* __restrict__ g,
                                          const float* __restrict__ b,
                                          float& sc, float& sh) {
    float sum = 0.f, ssq = 0.f;
#pragma unroll
    for (int cp = 0; cp < NCOPY; ++cp) {
        sum += st[cp * 128 + c];
        ssq += st[cp * 128 + 64 + c];
    }
    double mu  = (double)sum / (double)NND;
    double var = (double)ssq / (double)NND - mu * mu;
    if (var < 0.0) var = 0.0;
    double rs = 1.0 / sqrt(var + BN_EPS);
    double scd = (double)g[c] * rs;
    sc = (float)scd;
    sh = (float)((double)b[c] - mu * scd);
}

// ---------------- FUSED: transform (blocks [0,NT)) || degree count (blocks [NT,NT+PGRID)) ----
__global__ __launch_bounds__(256) void k_dtf(const int* __restrict__ dst,
                                             int* __restrict__ deg,
                                             const float* __restrict__ x,
                                             const float* __restrict__ Wt,
                                             const float* __restrict__ bt,
                                             unsigned* __restrict__ hB,
                                             float* __restrict__ stats) {
    __shared__ __align__(16) unsigned Wlu[NF * NH / 2]; // 16 KB, bf16-packed
    __shared__ __align__(16) float sT[64 * 68];         // 17.4 KB
    int tid = threadIdx.x;

    if (blockIdx.x >= NT) {
        // ---- degree-count body: batch all 4 stream loads up-front (ILP) ----
        int dbid = blockIdx.x - NT;
        int xcd = dbid & 7;
        int chunk = dbid >> 3;
        int lo = xcd * XNODES;
        const int4* d4 = (const int4*)dst;
        int4 d[4];
#pragma unroll
        for (int r = 0; r < 4; ++r) {
            int i = chunk * 1024 + r * 256 + tid;
            int ii = i < NE4 ? i : NE4 - 1;
            d[r] = d4[ii];
            if (i >= NE4) d[r] = make_int4(-1, -1, -1, -1);
        }
#pragma unroll
        for (int r = 0; r < 4; ++r) {
            if ((unsigned)(d[r].x - lo) < XNODES) atomicAdd(&deg[d[r].x], 1);
            if ((unsigned)(d[r].y - lo) < XNODES) atomicAdd(&deg[d[r].y], 1);
            if ((unsigned)(d[r].z - lo) < XNODES) atomicAdd(&deg[d[r].z], 1);
            if ((unsigned)(d[r].w - lo) < XNODES) atomicAdd(&deg[d[r].w], 1);
        }
        return;
    }

    // ---- transform body: one 64-node tile; all 256 threads stage, waves 0-1 compute ----
    int tile = blockIdx.x;
    int base = tile * 64;
    const float4* x4 = (const float4*)x;

#pragma unroll
    for (int r = 0; r < 8; ++r) {
        int i4 = r * 256 + tid;
        float4 w = ((const float4*)Wt)[i4];
        uint2 wp; wp.x = pk(w.x, w.y); wp.y = pk(w.z, w.w);
        ((uint2*)Wlu)[i4] = wp;
    }

    int wave = tid >> 6, lane = tid & 63;
    int ti = lane & 7, tj = lane >> 3;
    int cw = wave * 32 + tj * 4;          // compute waves 0-1: output cols

    float acc[8][4];
#pragma unroll
    for (int i = 0; i < 8; ++i)
#pragma unroll
        for (int j = 0; j < 4; ++j) acc[i][j] = 0.f;

    for (int ch = 0; ch < 2; ++ch) {
        __syncthreads();
        float4 pf[4];
#pragma unroll
        for (int s = 0; s < 4; ++s) {
            int flat = s * 256 + tid;
            int nl = flat >> 4, q = flat & 15;
            pf[s] = make_float4(0.f, 0.f, 0.f, 0.f);
            if (base + nl < NND) pf[s] = x4[(size_t)(base + nl) * 32 + ch * 16 + q];
        }
#pragma unroll
        for (int s = 0; s < 4; ++s) {
            int flat = s * 256 + tid;
            int nl = flat >> 4, q = flat & 15;
            sT[(q * 4 + 0) * 68 + nl] = pf[s].x;
            sT[(q * 4 + 1) * 68 + nl] = pf[s].y;
            sT[(q * 4 + 2) * 68 + nl] = pf[s].z;
            sT[(q * 4 + 3) * 68 + nl] = pf[s].w;
        }
        __syncthreads();
        if (tid < 128) {
#pragma unroll 4
            for (int k = 0; k < 64; ++k) {
                const float* ap = &sT[k * 68 + ti * 8];
                float4 alo = *(const float4*)ap;
                float4 ahi = *(const float4*)(ap + 4);
                uint2 wu = *(const uint2*)&Wlu[(ch * 64 + k) * 32 + (cw >> 1)];
                float a8[8] = {alo.x, alo.y, alo.z, alo.w, ahi.x, ahi.y, ahi.z, ahi.w};
                float w4[4] = {ulo(wu.x), uhi(wu.x), ulo(wu.y), uhi(wu.y)};
#pragma unroll
                for (int i = 0; i < 8; ++i)
#pragma unroll
                    for (int j = 0; j < 4; ++j) acc[i][j] += a8[i] * w4[j];
            }
        }
    }
    if (tid >= 128) return;

    float4 bv = *(const float4*)&bt[cw];
    float bj[4] = {bv.x, bv.y, bv.z, bv.w};

    float s4[4] = {0.f, 0.f, 0.f, 0.f}, q4[4] = {0.f, 0.f, 0.f, 0.f};
    uint2* hB2 = (uint2*)hB;
#pragma unroll
    for (int i = 0; i < 8; ++i) {
        int n = base + ti * 8 + i;
        if (n < NND) {
            float o[4];
#pragma unroll
            for (int j = 0; j < 4; ++j) {
                o[j] = acc[i][j] + bj[j];
                s4[j] += o[j];
                q4[j] += o[j] * o[j];
            }
            uint2 ov; ov.x = pk(o[0], o[1]); ov.y = pk(o[2], o[3]);
            hB2[(size_t)n * 16 + wave * 8 + tj] = ov;
        }
    }
#pragma unroll
    for (int m = 1; m < 8; m <<= 1) {
#pragma unroll
        for (int j = 0; j < 4; ++j) {
            s4[j] += __shfl_xor(s4[j], m);
            q4[j] += __shfl_xor(q4[j], m);
        }
    }
    if (ti == 0) {
        int slot = (tile & (NCOPY - 1)) * 128;
#pragma unroll
        for (int j = 0; j < 4; ++j) {
            atomicAdd(&stats[slot + cw + j], s4[j]);
            atomicAdd(&stats[slot + 64 + cw + j], q4[j]);
        }
    }
}

// ---------------- CSR fill: batch all 8 stream loads up-front (ILP) ----------------
__global__ __launch_bounds__(256) void k_fill(const int* __restrict__ src,
                                              const int* __restrict__ dst,
                                              int* __restrict__ cur,
                                              int* __restrict__ esrc) {
    int xcd = blockIdx.x & 7;
    int chunk = blockIdx.x >> 3;
    int lo = xcd * XNODES;
    const int4* d4 = (const int4*)dst;
    const int4* s4 = (const int4*)src;
    int4 d[4], s[4];
#pragma unroll
    for (int r = 0; r < 4; ++r) {
        int i = chunk * 1024 + r * 256 + threadIdx.x;
        int ii = i < NE4 ? i : NE4 - 1;
        d[r] = d4[ii];
        s[r] = s4[ii];
        if (i >= NE4) d[r] = make_int4(-1, -1, -1, -1);
    }
#pragma unroll
    for (int r = 0; r < 4; ++r) {
        if ((unsigned)(d[r].x - lo) < XNODES) esrc[atomicAdd(&cur[d[r].x], 1)] = s[r].x;
        if ((unsigned)(d[r].y - lo) < XNODES) esrc[atomicAdd(&cur[d[r].y], 1)] = s[r].y;
        if ((unsigned)(d[r].z - lo) < XNODES) esrc[atomicAdd(&cur[d[r].z], 1)] = s[r].z;
        if ((unsigned)(d[r].w - lo) < XNODES) esrc[atomicAdd(&cur[d[r].w], 1)] = s[r].w;
    }
}

// pass 1: per-256-chunk exclusive scan into offs, chunk totals into parts
__global__ __launch_bounds__(SCB) void k_part(const int* __restrict__ deg,
                                              int* __restrict__ offs,
                                              int* __restrict__ parts) {
    __shared__ int sd[SCB];
    int t = threadIdx.x;
    int i = blockIdx.x * SCB + t;
    int v = (i < NND) ? deg[i] : 0;
    sd[t] = v;
    __syncthreads();
#pragma unroll
    for (int off = 1; off < SCB; off <<= 1) {
        int u = (t >= off) ? sd[t - off] : 0;
        __syncthreads();
        sd[t] += u;
        __syncthreads();
    }
    if (i < NND) offs[i] = sd[t] - v;
    if (t == SCB - 1) parts[blockIdx.x] = sd[t];
}

// pass 2 (merged): each block redundantly scans the 196 partials in LDS,
// then applies its chunk offset and writes cur. Kills the separate k_scan2
// launch (one fewer serial dispatch in the CSR chain).
__global__ __launch_bounds__(256) void k_apply(int* __restrict__ offs,
                                               const int* __restrict__ parts,
                                               int* __restrict__ cur) {
    __shared__ int sd[256];
    int t = threadIdx.x;
    int v = (t < NSB) ? parts[t] : 0;
    sd[t] = v;
    __syncthreads();
#pragma unroll
    for (int off = 1; off < 256; off <<= 1) {
        int u = (t >= off) ? sd[t - off] : 0;
        __syncthreads();
        sd[t] += u;
        __syncthreads();
    }
    int c = blockIdx.x;
    int add = sd[c] - parts[c];   // exclusive prefix for this chunk
    int i = blockIdx.x * 256 + t;
    if (i < NND) {
        int o = offs[i] + add;
        offs[i] = o;
        cur[i] = o;
    }
    if (i == NND) offs[NND] = NED;
}

// ---------------- aggregation: wave-per-node, bf16 rows, 8 slots (R13 known-good) ----------------
__global__ __launch_bounds__(256) void k_agg(const uint4* __restrict__ hB4,
                                             uint4* __restrict__ aggB4,
                                             const float* __restrict__ stats,
                                             const float* __restrict__ g,
                                             const float* __restrict__ b,
                                             const int* __restrict__ offs,
                                             const int* __restrict__ esrc) {
    int tid  = threadIdx.x;
    int lane = tid & 63;
    int wv   = tid >> 6;
    int n = blockIdx.x * 4 + wv;
    int q = lane & 7;        // 16B sub-block within 128B row
    int r = lane >> 3;       // edge slot 0..7

    // per-lane BN derive for column `lane` (L2-hot 4KB)
    float scl, shl;
    bn_derive(stats, lane, g, b, scl, shl);

    int e0 = offs[n], e1 = offs[n + 1];
    int deg = e1 - e0;

    float a[8];
#pragma unroll
    for (int i = 0; i < 8; ++i) a[i] = 0.f;

    if (r == 0) {
        uint4 u = hB4[(size_t)n * 8 + q];
        upadd(u.x, a[0], a[1]); upadd(u.y, a[2], a[3]);
        upadd(u.z, a[4], a[5]); upadd(u.w, a[6], a[7]);
    }

    for (int bb = e0; bb < e1; bb += 64) {
        int m = e1 - bb; if (m > 64) m = 64;
        int idx = (lane < m) ? esrc[bb + lane] : 0;
        int t = 0;
        for (; t + 32 <= m; t += 32) {
            int j0 = __shfl(idx, t + r);
            int j1 = __shfl(idx, t + 8 + r);
            int j2 = __shfl(idx, t + 16 + r);
            int j3 = __shfl(idx, t + 24 + r);
            uint4 u0 = hB4[(size_t)j0 * 8 + q];
            uint4 u1 = hB4[(size_t)j1 * 8 + q];
            uint4 u2 = hB4[(size_t)j2 * 8 + q];
            uint4 u3 = hB4[(size_t)j3 * 8 + q];
            upadd(u0.x, a[0], a[1]); upadd(u0.y, a[2], a[3]);
            upadd(u0.z, a[4], a[5]); upadd(u0.w, a[6], a[7]);
            upadd(u1.x, a[0], a[1]); upadd(u1.y, a[2], a[3]);
            upadd(u1.z, a[4], a[5]); upadd(u1.w, a[6], a[7]);
            upadd(u2.x, a[0], a[1]); upadd(u2.y, a[2], a[3]);
            upadd(u2.z, a[4], a[5]); upadd(u2.w, a[6], a[7]);
            upadd(u3.x, a[0], a[1]); upadd(u3.y, a[2], a[3]);
            upadd(u3.z, a[4], a[5]); upadd(u3.w, a[6], a[7]);
        }
        for (; t < m; t += 8) {
            int e = t + r;
            int j = __shfl(idx, e & 63);
            if (e < m) {
                uint4 u = hB4[(size_t)j * 8 + q];
                upadd(u.x, a[0], a[1]); upadd(u.y, a[2], a[3]);
                upadd(u.z, a[4], a[5]); upadd(u.w, a[6], a[7]);
            }
        }
    }

#pragma unroll
    for (int msk = 8; msk <= 32; msk <<= 1)
#pragma unroll
        for (int i = 0; i < 8; ++i) a[i] += __shfl_xor(a[i], msk);

    // gather the 8 (sc,sh) pairs for this lane's columns q*8..q*8+7
    float sc8[8], sh8[8];
#pragma unroll
    for (int j = 0; j < 8; ++j) {
        sc8[j] = __shfl(scl, q * 8 + j);
        sh8[j] = __shfl(shl, q * 8 + j);
    }

    if (r == 0) {
        float dn = (float)(deg + 1);
        float o[8];
#pragma unroll
        for (int j = 0; j < 8; ++j) o[j] = sc8[j] * a[j] + dn * sh8[j];
        uint4 ov;
        ov.x = pk(o[0], o[1]); ov.y = pk(o[2], o[3]);
        ov.z = pk(o[4], o[5]); ov.w = pk(o[6], o[7]);
        aggB4[(size_t)n * 8 + q] = ov;
    }
}

// ---------------- MLP: col-split 1-tile blocks (2 waves, acc 8x4), 2 GEMMs ----------------
__global__ __launch_bounds__(128) void k_mlp(const uint4* __restrict__ aggB4,
                                             float* __restrict__ outF,    // f32 out (last layer) or null
                                             unsigned* __restrict__ hBo,  // bf16 out or null
                                             float* __restrict__ stats,
                                             const float* __restrict__ W1,
                                             const float* __restrict__ W2) {
    __shared__ __align__(16) float W1l[NH * NH];  // 16 KB
    __shared__ __align__(16) float W2l[NH * NH];  // 16 KB
    __shared__ __align__(16) float sT[64 * 68];   // 17.4 KB (agg, then t1)
    int tid  = threadIdx.x;
    int wave = tid >> 6, lane = tid & 63;
    int ti = lane & 7, tj = lane >> 3;
    int tile = blockIdx.x;
    int base = tile * 64;
    int cw = wave * 32 + tj * 4;

#pragma unroll
    for (int r = 0; r < 8; ++r) {
        int i4 = r * 128 + tid;
        ((float4*)W1l)[i4] = ((const float4*)W1)[i4];
        ((float4*)W2l)[i4] = ((const float4*)W2)[i4];
    }
#pragma unroll
    for (int s = 0; s < 4; ++s) {
        int i4 = s * 128 + tid;
        int nl = i4 >> 3, q = i4 & 7;
        uint4 u = make_uint4(0u, 0u, 0u, 0u);
        if (base + nl < NND) u = aggB4[(size_t)(base + nl) * 8 + q];
        sT[(q * 8 + 0) * 68 + nl] = ulo(u.x);
        sT[(q * 8 + 1) * 68 + nl] = uhi(u.x);
        sT[(q * 8 + 2) * 68 + nl] = ulo(u.y);
        sT[(q * 8 + 3) * 68 + nl] = uhi(u.y);
        sT[(q * 8 + 4) * 68 + nl] = ulo(u.z);
        sT[(q * 8 + 5) * 68 + nl] = uhi(u.z);
        sT[(q * 8 + 6) * 68 + nl] = ulo(u.w);
        sT[(q * 8 + 7) * 68 + nl] = uhi(u.w);
    }
    __syncthreads();

    float a1[8][4];
#pragma unroll
    for (int i = 0; i < 8; ++i)
#pragma unroll
        for (int j = 0; j < 4; ++j) a1[i][j] = 0.f;
#pragma unroll 4
    for (int k = 0; k < 64; ++k) {
        const float* ap = &sT[k * 68 + ti * 8];
        float4 alo = *(const float4*)ap;
        float4 ahi = *(const float4*)(ap + 4);
        float4 wv  = *(const float4*)&W1l[k * NH + cw];
        float a8[8] = {alo.x, alo.y, alo.z, alo.w, ahi.x, ahi.y, ahi.z, ahi.w};
        float w4[4] = {wv.x, wv.y, wv.z, wv.w};
#pragma unroll
        for (int i = 0; i < 8; ++i)
#pragma unroll
            for (int j = 0; j < 4; ++j) a1[i][j] += a8[i] * w4[j];
    }
#pragma unroll
    for (int i = 0; i < 8; ++i)
#pragma unroll
        for (int j = 0; j < 4; ++j) a1[i][j] = fmaxf(a1[i][j], 0.f);

    __syncthreads();
#pragma unroll
    for (int j = 0; j < 4; ++j) {
        float* p = &sT[(cw + j) * 68 + ti * 8];
        float4 lo = {a1[0][j], a1[1][j], a1[2][j], a1[3][j]};
        float4 hi = {a1[4][j], a1[5][j], a1[6][j], a1[7][j]};
        *(float4*)p = lo;
        *(float4*)(p + 4) = hi;
    }
    __syncthreads();

    float a2[8][4];
#pragma unroll
    for (int i = 0; i < 8; ++i)
#pragma unroll
        for (int j = 0; j < 4; ++j) a2[i][j] = 0.f;
#pragma unroll 4
    for (int k = 0; k < 64; ++k) {
        const float* ap = &sT[k * 68 + ti * 8];
        float4 alo = *(const float4*)ap;
        float4 ahi = *(const float4*)(ap + 4);
        float4 wv  = *(const float4*)&W2l[k * NH + cw];
        float a8[8] = {alo.x, alo.y, alo.z, alo.w, ahi.x, ahi.y, ahi.z, ahi.w};
        float w4[4] = {wv.x, wv.y, wv.z, wv.w};
#pragma unroll
        for (int i = 0; i < 8; ++i)
#pragma unroll
            for (int j = 0; j < 4; ++j) a2[i][j] += a8[i] * w4[j];
    }

    float s4[4] = {0.f, 0.f, 0.f, 0.f}, q4[4] = {0.f, 0.f, 0.f, 0.f};
    uint2* hBo2 = (uint2*)hBo;
#pragma unroll
    for (int i = 0; i < 8; ++i) {
        int n = base + ti * 8 + i;
        if (n < NND) {
            float o[4];
#pragma unroll
            for (int j = 0; j < 4; ++j) {
                o[j] = fmaxf(a2[i][j], 0.f);
                s4[j] += o[j];
                q4[j] += o[j] * o[j];
            }
            if (outF) *(float4*)&outF[(size_t)n * NH + cw] = *(float4*)&o[0];
            if (hBo) {
                uint2 ov; ov.x = pk(o[0], o[1]); ov.y = pk(o[2], o[3]);
                hBo2[(size_t)n * 16 + wave * 8 + tj] = ov;
            }
        }
    }
#pragma unroll
    for (int m = 1; m < 8; m <<= 1) {
#pragma unroll
        for (int j = 0; j < 4; ++j) {
            s4[j] += __shfl_xor(s4[j], m);
            q4[j] += __shfl_xor(q4[j], m);
        }
    }
    if (ti == 0) {
        int slot = (tile & (NCOPY - 1)) * 128;
#pragma unroll
        for (int j = 0; j < 4; ++j) {
            atomicAdd(&stats[slot + cw + j], s4[j]);
            atomicAdd(&stats[slot + 64 + cw + j], q4[j]);
        }
    }
}

// ---------------- final BN apply, in-place on f32 out; sc/sh derived per block ----------------
__global__ __launch_bounds__(256) void k_bnout(float* __restrict__ h,
                                               const float* __restrict__ stats,
                                               const float* __restrict__ g,
                                               const float* __restrict__ b) {
    __shared__ float sl[128];
    int tid = threadIdx.x;
    if (tid < 64) {
        float sc, sh;
        bn_derive(stats, tid, g, b, sc, sh);
        sl[tid]      = sc;
        sl[64 + tid] = sh;
    }
    __syncthreads();
    int i4 = blockIdx.x * 256 + tid;
    if (i4 < NND * NH / 4) {
        int cg = i4 & 15;
        float4 v   = ((float4*)h)[i4];
        float4 scv = *(float4*)&sl[cg * 4];
        float4 shv = *(float4*)&sl[64 + cg * 4];
        v.x = v.x * scv.x + shv.x;
        v.y = v.y * scv.y + shv.y;
        v.z = v.z * scv.z + shv.z;
        v.w = v.w * scv.w + shv.w;
        ((float4*)h)[i4] = v;
    }
}

extern "C" void kernel_launch(void* const* d_in, const int* in_sizes, int n_in,
                              void* d_out, int out_size, void* d_ws, size_t ws_size,
                              hipStream_t stream) {
    const float* x     = (const float*)d_in[0];
    const int*   ei    = (const int*)d_in[1];
    const float* Wt    = (const float*)d_in[2];
    const float* bt    = (const float*)d_in[3];
    const float* gt    = (const float*)d_in[4];
    const float* bbt   = (const float*)d_in[5];
    const float* W1    = (const float*)d_in[6];
    const float* W2    = (const float*)d_in[7];
    const float* gamma = (const float*)d_in[8];
    const float* beta  = (const float*)d_in[9];
    float* out = (float*)d_out;

    char* ws = (char*)d_ws;
    unsigned* hB    = (unsigned*)(ws + WS_HB);
    unsigned* aggB  = (unsigned*)(ws + WS_AGG);
    float*    stats = (float*)(ws + WS_STATS);   // 4 stage buffers of NCOPY*128
    int*      deg   = (int*)(ws + WS_DEG);
    int*      offs  = (int*)(ws + WS_OFFS);
    int*      cur   = (int*)(ws + WS_CUR);
    int*      parts = (int*)(ws + WS_PARTS);
    int*      esrc  = (int*)(ws + WS_ESRC);

    float* st0 = stats;
    float* st1 = stats + NCOPY * 128;
    float* st2 = stats + 2 * NCOPY * 128;
    float* st3 = stats + 3 * NCOPY * 128;

    const int* srcv = ei;
    const int* dstv = ei + NED;

    // one memset covers all 4 stat buffers + deg (contiguous)
    hipMemsetAsync(stats, 0, 4 * NCOPY * 128 * 4 + NND * 4, stream);

    // fused transform || degree count
    k_dtf<<<NT + PGRID, 256, 0, stream>>>(dstv, deg, x, Wt, bt, hB, st0);
    k_part<<<NSB, SCB, 0, stream>>>(deg, offs, parts);
    k_apply<<<NSB, 256, 0, stream>>>(offs, parts, cur);   // scan2 merged in
    k_fill<<<PGRID, 256, 0, stream>>>(srcv, dstv, cur, esrc);

    const int NB = NND / 4;         // 12500 agg blocks

    // layer 0: BN(st0; g_t) folded into agg
    k_agg<<<NB, 256, 0, stream>>>((const uint4*)hB, (uint4*)aggB, st0, gt, bbt, offs, esrc);
    k_mlp<<<NT, 128, 0, stream>>>((const uint4*)aggB, nullptr, hB, st1, W1, W2);

    // layer 1: BN(st1; gamma[0]) folded into agg
    k_agg<<<NB, 256, 0, stream>>>((const uint4*)hB, (uint4*)aggB, st1, gamma, beta, offs, esrc);
    k_mlp<<<NT, 128, 0, stream>>>((const uint4*)aggB, nullptr, hB, st2, W1 + 4096, W2 + 4096);

    // layer 2: BN(st2; gamma[1]) folded into agg; f32 out for final BN
    k_agg<<<NB, 256, 0, stream>>>((const uint4*)hB, (uint4*)aggB, st2, gamma + 64, beta + 64, offs, esrc);
    k_mlp<<<NT, 128, 0, stream>>>((const uint4*)aggB, out, nullptr, st3, W1 + 8192, W2 + 8192);

    // final BN apply (BN(st3; gamma[2]) derived per block)
    k_bnout<<<(NND * NH / 4 + 255) / 256, 256, 0, stream>>>(out, st3, gamma + 128, beta + 128);
}